// Round 1
// baseline (515.908 us; speedup 1.0000x reference)
//
#include <hip/hip_runtime.h>
#include <hip/hip_bf16.h>
#include <stdint.h>

#define DIM 1024
#define SEQ 2048
#define NB 4
#define HEADS 8
#define HD 128
#define ROWS (NB*SEQ)   // 8192

typedef __attribute__((ext_vector_type(8))) short bf16x8;
typedef __attribute__((ext_vector_type(4))) float f32x4;

static __device__ __forceinline__ unsigned short f2bf(float f){
  union { float f; unsigned int u; } x; x.f = f;
  unsigned int r = x.u + 0x7fffu + ((x.u >> 16) & 1u);
  return (unsigned short)(r >> 16);
}

static __device__ __forceinline__ void gld_lds16(const void* g, void* l){
  __builtin_amdgcn_global_load_lds(
      (const __attribute__((address_space(1))) void*)g,
      (__attribute__((address_space(3))) void*)l,
      16, 0, 0);
}

// ---------------- elementwise cast x -> bf16 ----------------
__global__ void k_cast(const float* __restrict__ src, unsigned short* __restrict__ dst, int n4){
  int i = blockIdx.x * blockDim.x + threadIdx.x;
  if (i >= n4) return;
  const float4 v = reinterpret_cast<const float4*>(src)[i];
  ushort4 o;
  o.x = f2bf(v.x); o.y = f2bf(v.y); o.z = f2bf(v.z); o.w = f2bf(v.w);
  reinterpret_cast<ushort4*>(dst)[i] = o;
}

// ---------------- transpose + cast weight [in][out] -> [out][in] bf16 ----------------
__global__ void k_transpose_cast(const float* __restrict__ W, unsigned short* __restrict__ WT){
  __shared__ float tile[64][65];
  const int tid = threadIdx.x;
  const int bi = blockIdx.y * 64;  // input-row block (k)
  const int bo = blockIdx.x * 64;  // input-col block (out)
  #pragma unroll
  for (int it = 0; it < 16; ++it){
    int f = it*256 + tid;
    int r = f >> 6, c = f & 63;
    tile[r][c] = W[(size_t)(bi + r) * DIM + bo + c];
  }
  __syncthreads();
  #pragma unroll
  for (int it = 0; it < 16; ++it){
    int f = it*256 + tid;
    int r = f >> 6, c = f & 63;   // output row r = out index, col c = k index
    WT[(size_t)(bo + r) * DIM + bi + c] = f2bf(tile[c][r]);
  }
}

// ---------------- fused K/V projection GEMM ----------------
// C tiles: rows = (n,s) flattened [8192], cols = (h,d) [1024].
// Epilogue: ek = exp(k+bk), ekv = ek*(v+bv), write bf16 into
// ekb[h][n*256 + d]{den part} / [n*256 + 128 + d]{num part} over s (transposed for core B staging).
__global__ __launch_bounds__(256) void k_proj(
    const unsigned short* __restrict__ xb,
    const unsigned short* __restrict__ wkt,
    const unsigned short* __restrict__ wvt,
    const float* __restrict__ bk,
    const float* __restrict__ bv,
    unsigned short* __restrict__ ekb)
{
  __shared__ unsigned short Al[128*64];
  __shared__ unsigned short Bkl[128*64];
  __shared__ unsigned short Bvl[128*64];
  const int tid  = threadIdx.x;
  const int lane = tid & 63;
  const int wr   = tid >> 7;
  const int wc   = (tid >> 6) & 1;
  const int row0 = blockIdx.x * 128;
  const int col0 = blockIdx.y * 128;

  f32x4 acck[4][4] = {};
  f32x4 accv[4][4] = {};

  for (int kt = 0; kt < DIM/64; ++kt){
    const int kbase = kt * 64;
    #pragma unroll
    for (int it = 0; it < 4; ++it){
      const int o = it*4096 + tid*16;     // LDS byte offset (lane-linear)
      const int r = o >> 7;               // 128 B per row (64 bf16)
      const int k = (o & 127) >> 1;
      gld_lds16(xb  + (size_t)(row0 + r)*DIM + kbase + k, (char*)Al  + o);
      gld_lds16(wkt + (size_t)(col0 + r)*DIM + kbase + k, (char*)Bkl + o);
      gld_lds16(wvt + (size_t)(col0 + r)*DIM + kbase + k, (char*)Bvl + o);
    }
    __syncthreads();
    #pragma unroll
    for (int ks = 0; ks < 2; ++ks){
      const int k0 = ks*32 + ((lane >> 4) << 3);
      bf16x8 af[4], bkf[4], bvf[4];
      #pragma unroll
      for (int i = 0; i < 4; ++i)
        af[i] = *reinterpret_cast<const bf16x8*>(&Al[(wr*64 + i*16 + (lane&15))*64 + k0]);
      #pragma unroll
      for (int j = 0; j < 4; ++j){
        bkf[j] = *reinterpret_cast<const bf16x8*>(&Bkl[(wc*64 + j*16 + (lane&15))*64 + k0]);
        bvf[j] = *reinterpret_cast<const bf16x8*>(&Bvl[(wc*64 + j*16 + (lane&15))*64 + k0]);
      }
      #pragma unroll
      for (int i = 0; i < 4; ++i)
        #pragma unroll
        for (int j = 0; j < 4; ++j){
          acck[i][j] = __builtin_amdgcn_mfma_f32_16x16x32_bf16(af[i], bkf[j], acck[i][j], 0, 0, 0);
          accv[i][j] = __builtin_amdgcn_mfma_f32_16x16x32_bf16(af[i], bvf[j], accv[i][j], 0, 0, 0);
        }
    }
    __syncthreads();
  }

  #pragma unroll
  for (int j = 0; j < 4; ++j){
    const int c = col0 + wc*64 + j*16 + (lane & 15);
    const int h = c >> 7;
    const int d = c & 127;
    const float bkc = bk[c];
    const float bvc = bv[c];
    #pragma unroll
    for (int i = 0; i < 4; ++i){
      #pragma unroll
      for (int jj = 0; jj < 4; ++jj){
        const int r = row0 + wr*64 + i*16 + ((lane>>4)<<2) + jj;
        const int n = r >> 11;
        const int s = r & 2047;
        const float kval = acck[i][j][jj] + bkc;
        const float vval = accv[i][j][jj] + bvc;
        const float ek  = __expf(kval);
        const float ekv = ek * vval;
        const size_t idx = ((size_t)h*1024 + n*256 + d) * SEQ + s;
        ekb[idx] = f2bf(ek);
        ekb[idx + (size_t)128*SEQ] = f2bf(ekv);
      }
    }
  }
}

// ---------------- AFT causal core ----------------
// Per (h, n, t-tile): C[128 t][256 c] = sum_s exp(w_aft[h][t][s]) * B[s][c], s <= t only.
// c in [0,128): den (ek columns); c in [128,256): num (ekv columns).
__global__ __launch_bounds__(256) void k_core(
    const float* __restrict__ waft,
    const unsigned short* __restrict__ ekb,
    float* __restrict__ dens,
    float* __restrict__ nums)
{
  __shared__ unsigned short Al[128*64];  // ew tile [t][s]
  __shared__ unsigned short Bl[256*64];  // [c][s]
  const int tid  = threadIdx.x;
  const int lane = tid & 63;
  const int wr   = tid >> 7;
  const int wc   = (tid >> 6) & 1;
  const int tt = blockIdx.x;
  const int n  = blockIdx.y;
  const int h  = blockIdx.z;
  const int t0 = tt * 128;
  const int nkt = 2*tt + 2;   // causal: only s-tiles with s0 <= t0+127

  const float* wbase = waft + (size_t)h * SEQ * SEQ;
  const unsigned short* bbase = ekb + ((size_t)h*1024 + n*256) * SEQ;

  f32x4 acc[4][8] = {};

  for (int st = 0; st < nkt; ++st){
    const int s0 = st * 64;
    // stage B via global_load_lds (contiguous along s)
    #pragma unroll
    for (int it = 0; it < 8; ++it){
      const int o = it*4096 + tid*16;
      const int c = o >> 7;
      const int k = (o & 127) >> 1;
      gld_lds16(bbase + (size_t)c*SEQ + s0 + k, (char*)Bl + o);
    }
    // stage A: load w_aft, fused exp + causal mask, pack bf16
    #pragma unroll
    for (int it = 0; it < 8; ++it){
      const int f = (it*256 + tid) * 4;
      const int r  = f >> 6;
      const int cc = f & 63;
      const int tg = t0 + r;
      const float4 w4 = *reinterpret_cast<const float4*>(wbase + (size_t)tg*SEQ + s0 + cc);
      ushort4 o4;
      o4.x = (s0+cc+0 <= tg) ? f2bf(__expf(w4.x)) : (unsigned short)0;
      o4.y = (s0+cc+1 <= tg) ? f2bf(__expf(w4.y)) : (unsigned short)0;
      o4.z = (s0+cc+2 <= tg) ? f2bf(__expf(w4.z)) : (unsigned short)0;
      o4.w = (s0+cc+3 <= tg) ? f2bf(__expf(w4.w)) : (unsigned short)0;
      *reinterpret_cast<ushort4*>(&Al[r*64 + cc]) = o4;
    }
    __syncthreads();
    #pragma unroll
    for (int ks = 0; ks < 2; ++ks){
      const int k0 = ks*32 + ((lane >> 4) << 3);
      bf16x8 af[4], bfr[8];
      #pragma unroll
      for (int i = 0; i < 4; ++i)
        af[i] = *reinterpret_cast<const bf16x8*>(&Al[(wr*64 + i*16 + (lane&15))*64 + k0]);
      #pragma unroll
      for (int j = 0; j < 8; ++j)
        bfr[j] = *reinterpret_cast<const bf16x8*>(&Bl[(wc*128 + j*16 + (lane&15))*64 + k0]);
      #pragma unroll
      for (int i = 0; i < 4; ++i)
        #pragma unroll
        for (int j = 0; j < 8; ++j)
          acc[i][j] = __builtin_amdgcn_mfma_f32_16x16x32_bf16(af[i], bfr[j], acc[i][j], 0, 0, 0);
    }
    __syncthreads();
  }

  #pragma unroll
  for (int j = 0; j < 8; ++j){
    const int c = wc*128 + j*16 + (lane & 15);
    float* const outp = (c < 128) ? dens : nums;
    const int d = c & 127;
    #pragma unroll
    for (int i = 0; i < 4; ++i){
      #pragma unroll
      for (int jj = 0; jj < 4; ++jj){
        const int t = t0 + wr*64 + i*16 + ((lane>>4)<<2) + jj;
        outp[((size_t)n*SEQ + t)*DIM + h*HD + d] = acc[i][j][jj];
      }
    }
  }
}

// ---------------- aft = num/den, cast bf16 ----------------
__global__ void k_div(const float* __restrict__ nums, const float* __restrict__ dens,
                      unsigned short* __restrict__ aftb, int n4){
  int i = blockIdx.x * blockDim.x + threadIdx.x;
  if (i >= n4) return;
  float4 nu = reinterpret_cast<const float4*>(nums)[i];
  float4 de = reinterpret_cast<const float4*>(dens)[i];
  ushort4 o;
  o.x = f2bf(nu.x/de.x); o.y = f2bf(nu.y/de.y);
  o.z = f2bf(nu.z/de.z); o.w = f2bf(nu.w/de.w);
  reinterpret_cast<ushort4*>(aftb)[i] = o;
}

// ---------------- output projection GEMM + bias ----------------
__global__ __launch_bounds__(256) void k_out(
    const unsigned short* __restrict__ aftb,
    const unsigned short* __restrict__ wot,
    const float* __restrict__ bo,
    float* __restrict__ out)
{
  __shared__ unsigned short Al[128*64];
  __shared__ unsigned short Bl[128*64];
  const int tid  = threadIdx.x;
  const int lane = tid & 63;
  const int wr   = tid >> 7;
  const int wc   = (tid >> 6) & 1;
  const int row0 = blockIdx.x * 128;
  const int col0 = blockIdx.y * 128;

  f32x4 acc[4][4] = {};

  for (int kt = 0; kt < DIM/64; ++kt){
    const int kbase = kt * 64;
    #pragma unroll
    for (int it = 0; it < 4; ++it){
      const int o = it*4096 + tid*16;
      const int r = o >> 7;
      const int k = (o & 127) >> 1;
      gld_lds16(aftb + (size_t)(row0 + r)*DIM + kbase + k, (char*)Al + o);
      gld_lds16(wot  + (size_t)(col0 + r)*DIM + kbase + k, (char*)Bl + o);
    }
    __syncthreads();
    #pragma unroll
    for (int ks = 0; ks < 2; ++ks){
      const int k0 = ks*32 + ((lane >> 4) << 3);
      bf16x8 af[4], bfr[4];
      #pragma unroll
      for (int i = 0; i < 4; ++i)
        af[i] = *reinterpret_cast<const bf16x8*>(&Al[(wr*64 + i*16 + (lane&15))*64 + k0]);
      #pragma unroll
      for (int j = 0; j < 4; ++j)
        bfr[j] = *reinterpret_cast<const bf16x8*>(&Bl[(wc*64 + j*16 + (lane&15))*64 + k0]);
      #pragma unroll
      for (int i = 0; i < 4; ++i)
        #pragma unroll
        for (int j = 0; j < 4; ++j)
          acc[i][j] = __builtin_amdgcn_mfma_f32_16x16x32_bf16(af[i], bfr[j], acc[i][j], 0, 0, 0);
    }
    __syncthreads();
  }

  #pragma unroll
  for (int j = 0; j < 4; ++j){
    const int c = col0 + wc*64 + j*16 + (lane & 15);
    const float boc = bo[c];
    #pragma unroll
    for (int i = 0; i < 4; ++i){
      #pragma unroll
      for (int jj = 0; jj < 4; ++jj){
        const int r = row0 + wr*64 + i*16 + ((lane>>4)<<2) + jj;
        out[(size_t)r*DIM + c] = acc[i][j][jj] + boc;
      }
    }
  }
}

extern "C" void kernel_launch(void* const* d_in, const int* in_sizes, int n_in,
                              void* d_out, int out_size, void* d_ws, size_t ws_size,
                              hipStream_t stream){
  const float* x    = (const float*)d_in[0];
  const float* Wk   = (const float*)d_in[1];
  const float* bk   = (const float*)d_in[2];
  const float* Wv   = (const float*)d_in[3];
  const float* bv   = (const float*)d_in[4];
  const float* waft = (const float*)d_in[5];
  const float* Wo   = (const float*)d_in[6];
  const float* bo   = (const float*)d_in[7];
  float* out = (float*)d_out;

  char* w = (char*)d_ws;
  unsigned short* xb   = (unsigned short*)w; w += (size_t)ROWS*DIM*2;       // 16 MB
  unsigned short* wkt  = (unsigned short*)w; w += (size_t)DIM*DIM*2;        // 2 MB
  unsigned short* wvt  = (unsigned short*)w; w += (size_t)DIM*DIM*2;        // 2 MB
  unsigned short* wot  = (unsigned short*)w; w += (size_t)DIM*DIM*2;        // 2 MB
  unsigned short* ekb  = (unsigned short*)w; w += (size_t)HEADS*1024*SEQ*2; // 32 MB
  float* dens          = (float*)w;          w += (size_t)NB*SEQ*DIM*4;     // 32 MB
  float* nums          = (float*)w;          w += (size_t)NB*SEQ*DIM*4;     // 32 MB
  unsigned short* aftb = (unsigned short*)w; w += (size_t)ROWS*DIM*2;       // 16 MB

  k_cast<<<ROWS*DIM/4/256, 256, 0, stream>>>(x, xb, ROWS*DIM/4);
  k_transpose_cast<<<dim3(16,16), 256, 0, stream>>>(Wk, wkt);
  k_transpose_cast<<<dim3(16,16), 256, 0, stream>>>(Wv, wvt);
  k_transpose_cast<<<dim3(16,16), 256, 0, stream>>>(Wo, wot);
  k_proj<<<dim3(64, 8), 256, 0, stream>>>(xb, wkt, wvt, bk, bv, ekb);
  k_core<<<dim3(16, 4, 8), 256, 0, stream>>>(waft, ekb, dens, nums);
  k_div<<<ROWS*DIM/4/256, 256, 0, stream>>>(nums, dens, aftb, ROWS*DIM/4);
  k_out<<<dim3(64, 8), 256, 0, stream>>>(aftb, wot, bo, out);
}

// Round 2
// 216.050 us; speedup vs baseline: 2.3879x; 2.3879x over previous
//
#include <hip/hip_runtime.h>
#include <hip/hip_bf16.h>
#include <stdint.h>

#define DIM 1024
#define SEQ 2048
#define NB 4
#define HEADS 8
#define HD 128
#define ROWS (NB*SEQ)   // 8192

typedef __attribute__((ext_vector_type(8))) short bf16x8;
typedef __attribute__((ext_vector_type(4))) float f32x4;

static __device__ __forceinline__ unsigned short f2bf(float f){
  union { float f; unsigned int u; } x; x.f = f;
  unsigned int r = x.u + 0x7fffu + ((x.u >> 16) & 1u);
  return (unsigned short)(r >> 16);
}

static __device__ __forceinline__ void gld_lds16(const void* g, void* l){
  __builtin_amdgcn_global_load_lds(
      (const __attribute__((address_space(1))) void*)g,
      (__attribute__((address_space(3))) void*)l,
      16, 0, 0);
}

// ---------------- elementwise cast x -> bf16 ----------------
__global__ void k_cast(const float* __restrict__ src, unsigned short* __restrict__ dst, int n4){
  int i = blockIdx.x * blockDim.x + threadIdx.x;
  if (i >= n4) return;
  const float4 v = reinterpret_cast<const float4*>(src)[i];
  ushort4 o;
  o.x = f2bf(v.x); o.y = f2bf(v.y); o.z = f2bf(v.z); o.w = f2bf(v.w);
  reinterpret_cast<ushort4*>(dst)[i] = o;
}

// ---------------- transpose + cast weight [in][out] -> [out][in] bf16 ----------------
__global__ void k_transpose_cast(const float* __restrict__ W, unsigned short* __restrict__ WT){
  __shared__ float tile[64][65];
  const int tid = threadIdx.x;
  const int bi = blockIdx.y * 64;  // input-row block (k)
  const int bo = blockIdx.x * 64;  // input-col block (out)
  #pragma unroll
  for (int it = 0; it < 16; ++it){
    int f = it*256 + tid;
    int r = f >> 6, c = f & 63;
    tile[r][c] = W[(size_t)(bi + r) * DIM + bo + c];
  }
  __syncthreads();
  #pragma unroll
  for (int it = 0; it < 16; ++it){
    int f = it*256 + tid;
    int r = f >> 6, c = f & 63;
    WT[(size_t)(bo + r) * DIM + bi + c] = f2bf(tile[c][r]);
  }
}

// ---------------- precompute ewb[h][t][s] = (s<=t) ? bf16(exp(w_aft)) : 0 ----------------
// Only writes s in [0, (t & ~127) + 128) — the region k_core ever reads.
__global__ void k_ew(const float* __restrict__ waft, unsigned short* __restrict__ ewb){
  const int t = blockIdx.x;
  const int h = blockIdx.y;
  const float* src = waft + ((size_t)h*SEQ + t) * SEQ;
  unsigned short* dst = ewb + ((size_t)h*SEQ + t) * SEQ;
  const int smax4 = ((t & ~127) + 128) >> 2;
  for (int i = threadIdx.x; i < smax4; i += blockDim.x){
    const float4 w4 = reinterpret_cast<const float4*>(src)[i];
    const int s = i * 4;
    ushort4 o;
    o.x = (s+0 <= t) ? f2bf(__expf(w4.x)) : (unsigned short)0;
    o.y = (s+1 <= t) ? f2bf(__expf(w4.y)) : (unsigned short)0;
    o.z = (s+2 <= t) ? f2bf(__expf(w4.z)) : (unsigned short)0;
    o.w = (s+3 <= t) ? f2bf(__expf(w4.w)) : (unsigned short)0;
    reinterpret_cast<ushort4*>(dst)[i] = o;
  }
}

// ---------------- fused K/V projection GEMM ----------------
__global__ __launch_bounds__(256) void k_proj(
    const unsigned short* __restrict__ xb,
    const unsigned short* __restrict__ wkt,
    const unsigned short* __restrict__ wvt,
    const float* __restrict__ bk,
    const float* __restrict__ bv,
    unsigned short* __restrict__ ekb)
{
  __shared__ unsigned short Al[128*64];
  __shared__ unsigned short Bkl[128*64];
  __shared__ unsigned short Bvl[128*64];
  const int tid  = threadIdx.x;
  const int lane = tid & 63;
  const int wr   = tid >> 7;
  const int wc   = (tid >> 6) & 1;
  const int row0 = blockIdx.x * 128;
  const int col0 = blockIdx.y * 128;

  f32x4 acck[4][4] = {};
  f32x4 accv[4][4] = {};

  for (int kt = 0; kt < DIM/64; ++kt){
    const int kbase = kt * 64;
    #pragma unroll
    for (int it = 0; it < 4; ++it){
      const int o = it*4096 + tid*16;
      const int r = o >> 7;
      const int k = (o & 127) >> 1;
      gld_lds16(xb  + (size_t)(row0 + r)*DIM + kbase + k, (char*)Al  + o);
      gld_lds16(wkt + (size_t)(col0 + r)*DIM + kbase + k, (char*)Bkl + o);
      gld_lds16(wvt + (size_t)(col0 + r)*DIM + kbase + k, (char*)Bvl + o);
    }
    __syncthreads();
    #pragma unroll
    for (int ks = 0; ks < 2; ++ks){
      const int k0 = ks*32 + ((lane >> 4) << 3);
      bf16x8 af[4], bkf[4], bvf[4];
      #pragma unroll
      for (int i = 0; i < 4; ++i)
        af[i] = *reinterpret_cast<const bf16x8*>(&Al[(wr*64 + i*16 + (lane&15))*64 + k0]);
      #pragma unroll
      for (int j = 0; j < 4; ++j){
        bkf[j] = *reinterpret_cast<const bf16x8*>(&Bkl[(wc*64 + j*16 + (lane&15))*64 + k0]);
        bvf[j] = *reinterpret_cast<const bf16x8*>(&Bvl[(wc*64 + j*16 + (lane&15))*64 + k0]);
      }
      #pragma unroll
      for (int i = 0; i < 4; ++i)
        #pragma unroll
        for (int j = 0; j < 4; ++j){
          acck[i][j] = __builtin_amdgcn_mfma_f32_16x16x32_bf16(af[i], bkf[j], acck[i][j], 0, 0, 0);
          accv[i][j] = __builtin_amdgcn_mfma_f32_16x16x32_bf16(af[i], bvf[j], accv[i][j], 0, 0, 0);
        }
    }
    __syncthreads();
  }

  #pragma unroll
  for (int j = 0; j < 4; ++j){
    const int c = col0 + wc*64 + j*16 + (lane & 15);
    const int h = c >> 7;
    const int d = c & 127;
    const float bkc = bk[c];
    const float bvc = bv[c];
    #pragma unroll
    for (int i = 0; i < 4; ++i){
      #pragma unroll
      for (int jj = 0; jj < 4; ++jj){
        const int r = row0 + wr*64 + i*16 + ((lane>>4)<<2) + jj;
        const int n = r >> 11;
        const int s = r & 2047;
        const float kval = acck[i][j][jj] + bkc;
        const float vval = accv[i][j][jj] + bvc;
        const float ek  = __expf(kval);
        const float ekv = ek * vval;
        const size_t idx = ((size_t)h*1024 + n*256 + d) * SEQ + s;
        ekb[idx] = f2bf(ek);
        ekb[idx + (size_t)128*SEQ] = f2bf(ekv);
      }
    }
  }
}

// ---------------- AFT causal core ----------------
// Triangle-paired, column-split, double-buffered.
// Block (bx, n, h): p = bx>>1 pairs t-tiles {15-p, p}; ch = bx&1 selects den (0) / num (1) columns.
// Per t-tile: C[128 t][128 d] = sum_s ewb[h][t][s] * ekb[(h,n,ch*128+d)][s], s-tiles 0..2tt+1.
__global__ __launch_bounds__(256) void k_core(
    const unsigned short* __restrict__ ewb,
    const unsigned short* __restrict__ ekb,
    float* __restrict__ dens,
    float* __restrict__ nums)
{
  __shared__ unsigned short Al[2][128*64];
  __shared__ unsigned short Bl[2][128*64];
  const int tid  = threadIdx.x;
  const int lane = tid & 63;
  const int wr   = tid >> 7;
  const int wc   = (tid >> 6) & 1;
  const int p  = blockIdx.x >> 1;
  const int ch = blockIdx.x & 1;
  const int n  = blockIdx.y;
  const int h  = blockIdx.z;

  const unsigned short* bbase = ekb + ((size_t)h*1024 + n*256 + ch*128) * SEQ;
  float* const outp = ch ? nums : dens;

  #pragma unroll
  for (int half = 0; half < 2; ++half){
    const int tt = half ? p : (15 - p);
    const int t0 = tt * 128;
    const int nst = 2*tt + 2;
    const unsigned short* abase = ewb + ((size_t)h*SEQ + t0) * SEQ;

    f32x4 acc[4][4] = {};

    // prologue: stage s-tile 0 into buf 0
    {
      const int o = tid*16;
      #pragma unroll
      for (int it = 0; it < 4; ++it){
        const int oo = it*4096 + o;
        const int r = oo >> 7;
        const int k = (oo & 127) >> 1;
        gld_lds16(abase + (size_t)r*SEQ + k, (char*)&Al[0][0] + oo);
        gld_lds16(bbase + (size_t)r*SEQ + k, (char*)&Bl[0][0] + oo);
      }
    }
    __syncthreads();

    int cur = 0;
    for (int st = 0; st < nst; ++st){
      if (st + 1 < nst){
        const int s0 = (st + 1) * 64;
        #pragma unroll
        for (int it = 0; it < 4; ++it){
          const int oo = it*4096 + tid*16;
          const int r = oo >> 7;
          const int k = (oo & 127) >> 1;
          gld_lds16(abase + (size_t)r*SEQ + s0 + k, (char*)&Al[cur^1][0] + oo);
          gld_lds16(bbase + (size_t)r*SEQ + s0 + k, (char*)&Bl[cur^1][0] + oo);
        }
      }
      #pragma unroll
      for (int ks = 0; ks < 2; ++ks){
        const int k0 = ks*32 + ((lane >> 4) << 3);
        bf16x8 af[4], bfr[4];
        #pragma unroll
        for (int i = 0; i < 4; ++i)
          af[i] = *reinterpret_cast<const bf16x8*>(&Al[cur][(wr*64 + i*16 + (lane&15))*64 + k0]);
        #pragma unroll
        for (int j = 0; j < 4; ++j)
          bfr[j] = *reinterpret_cast<const bf16x8*>(&Bl[cur][(wc*64 + j*16 + (lane&15))*64 + k0]);
        #pragma unroll
        for (int i = 0; i < 4; ++i)
          #pragma unroll
          for (int j = 0; j < 4; ++j)
            acc[i][j] = __builtin_amdgcn_mfma_f32_16x16x32_bf16(af[i], bfr[j], acc[i][j], 0, 0, 0);
      }
      __syncthreads();   // drains vmcnt (prefetch) + lgkm; safe to flip
      cur ^= 1;
    }

    #pragma unroll
    for (int j = 0; j < 4; ++j){
      const int d = wc*64 + j*16 + (lane & 15);
      #pragma unroll
      for (int i = 0; i < 4; ++i){
        #pragma unroll
        for (int jj = 0; jj < 4; ++jj){
          const int t = t0 + wr*64 + i*16 + ((lane>>4)<<2) + jj;
          outp[((size_t)n*SEQ + t)*DIM + h*HD + d] = acc[i][j][jj];
        }
      }
    }
    __syncthreads();
  }
}

// ---------------- aft = num/den, cast bf16 ----------------
__global__ void k_div(const float* __restrict__ nums, const float* __restrict__ dens,
                      unsigned short* __restrict__ aftb, int n4){
  int i = blockIdx.x * blockDim.x + threadIdx.x;
  if (i >= n4) return;
  float4 nu = reinterpret_cast<const float4*>(nums)[i];
  float4 de = reinterpret_cast<const float4*>(dens)[i];
  ushort4 o;
  o.x = f2bf(nu.x/de.x); o.y = f2bf(nu.y/de.y);
  o.z = f2bf(nu.z/de.z); o.w = f2bf(nu.w/de.w);
  reinterpret_cast<ushort4*>(aftb)[i] = o;
}

// ---------------- output projection GEMM + bias ----------------
__global__ __launch_bounds__(256) void k_out(
    const unsigned short* __restrict__ aftb,
    const unsigned short* __restrict__ wot,
    const float* __restrict__ bo,
    float* __restrict__ out)
{
  __shared__ unsigned short Al[128*64];
  __shared__ unsigned short Bl[128*64];
  const int tid  = threadIdx.x;
  const int lane = tid & 63;
  const int wr   = tid >> 7;
  const int wc   = (tid >> 6) & 1;
  const int row0 = blockIdx.x * 128;
  const int col0 = blockIdx.y * 128;

  f32x4 acc[4][4] = {};

  for (int kt = 0; kt < DIM/64; ++kt){
    const int kbase = kt * 64;
    #pragma unroll
    for (int it = 0; it < 4; ++it){
      const int o = it*4096 + tid*16;
      const int r = o >> 7;
      const int k = (o & 127) >> 1;
      gld_lds16(aftb + (size_t)(row0 + r)*DIM + kbase + k, (char*)Al + o);
      gld_lds16(wot  + (size_t)(col0 + r)*DIM + kbase + k, (char*)Bl + o);
    }
    __syncthreads();
    #pragma unroll
    for (int ks = 0; ks < 2; ++ks){
      const int k0 = ks*32 + ((lane >> 4) << 3);
      bf16x8 af[4], bfr[4];
      #pragma unroll
      for (int i = 0; i < 4; ++i)
        af[i] = *reinterpret_cast<const bf16x8*>(&Al[(wr*64 + i*16 + (lane&15))*64 + k0]);
      #pragma unroll
      for (int j = 0; j < 4; ++j)
        bfr[j] = *reinterpret_cast<const bf16x8*>(&Bl[(wc*64 + j*16 + (lane&15))*64 + k0]);
      #pragma unroll
      for (int i = 0; i < 4; ++i)
        #pragma unroll
        for (int j = 0; j < 4; ++j)
          acc[i][j] = __builtin_amdgcn_mfma_f32_16x16x32_bf16(af[i], bfr[j], acc[i][j], 0, 0, 0);
    }
    __syncthreads();
  }

  #pragma unroll
  for (int j = 0; j < 4; ++j){
    const int c = col0 + wc*64 + j*16 + (lane & 15);
    const float boc = bo[c];
    #pragma unroll
    for (int i = 0; i < 4; ++i){
      #pragma unroll
      for (int jj = 0; jj < 4; ++jj){
        const int r = row0 + wr*64 + i*16 + ((lane>>4)<<2) + jj;
        out[(size_t)r*DIM + c] = acc[i][j][jj] + boc;
      }
    }
  }
}

extern "C" void kernel_launch(void* const* d_in, const int* in_sizes, int n_in,
                              void* d_out, int out_size, void* d_ws, size_t ws_size,
                              hipStream_t stream){
  const float* x    = (const float*)d_in[0];
  const float* Wk   = (const float*)d_in[1];
  const float* bk   = (const float*)d_in[2];
  const float* Wv   = (const float*)d_in[3];
  const float* bv   = (const float*)d_in[4];
  const float* waft = (const float*)d_in[5];
  const float* Wo   = (const float*)d_in[6];
  const float* bo   = (const float*)d_in[7];
  float* out = (float*)d_out;

  char* w = (char*)d_ws;
  unsigned short* xb   = (unsigned short*)w; w += (size_t)ROWS*DIM*2;       // 16 MB
  unsigned short* wkt  = (unsigned short*)w; w += (size_t)DIM*DIM*2;        // 2 MB
  unsigned short* wvt  = (unsigned short*)w; w += (size_t)DIM*DIM*2;        // 2 MB
  unsigned short* wot  = (unsigned short*)w; w += (size_t)DIM*DIM*2;        // 2 MB
  unsigned short* ekb  = (unsigned short*)w; w += (size_t)HEADS*1024*SEQ*2; // 32 MB
  float* dens          = (float*)w;          w += (size_t)NB*SEQ*DIM*4;     // 32 MB
  float* nums          = (float*)w;          w += (size_t)NB*SEQ*DIM*4;     // 32 MB
  unsigned short* aftb = (unsigned short*)w; w += (size_t)ROWS*DIM*2;       // 16 MB
  unsigned short* ewb  = (unsigned short*)w; w += (size_t)HEADS*SEQ*SEQ*2;  // 64 MB

  k_cast<<<ROWS*DIM/4/256, 256, 0, stream>>>(x, xb, ROWS*DIM/4);
  k_transpose_cast<<<dim3(16,16), 256, 0, stream>>>(Wk, wkt);
  k_transpose_cast<<<dim3(16,16), 256, 0, stream>>>(Wv, wvt);
  k_transpose_cast<<<dim3(16,16), 256, 0, stream>>>(Wo, wot);
  k_ew<<<dim3(SEQ, HEADS), 256, 0, stream>>>(waft, ewb);
  k_proj<<<dim3(64, 8), 256, 0, stream>>>(xb, wkt, wvt, bk, bv, ekb);
  k_core<<<dim3(16, NB, HEADS), 256, 0, stream>>>(ewb, ekb, dens, nums);
  k_div<<<ROWS*DIM/4/256, 256, 0, stream>>>(nums, dens, aftb, ROWS*DIM/4);
  k_out<<<dim3(64, 8), 256, 0, stream>>>(aftb, wot, bo, out);
}